// Round 8
// baseline (114.291 us; speedup 1.0000x reference)
//
#include <hip/hip_runtime.h>
#include <math.h>

#define DIM 4096
#define ROWS 2048
#define SB 68   // image stride in halves: half4 writes 8B-aligned; u16 frag
                // reads 2 words/bank + same-word broadcast = conflict-free

typedef _Float16 half8  __attribute__((ext_vector_type(8)));
typedef _Float16 half4  __attribute__((ext_vector_type(4)));
typedef float    float4e __attribute__((ext_vector_type(4)));

// One column-tile of an "H on the left" stage: acc(I) = sum_Kt H(I,Kt) x B(Kt),
// B[k][n'] = img[k*SB + 16J+n'] (this wave's J only), k = 32Kt + 8q + j.
__device__ __forceinline__ void hx_stage(const _Float16* __restrict__ img,
                                         int n, int q, int J,
                                         const half8 Hf[4][2], float4e acc[4]) {
    half8 B[2];
#pragma unroll
    for (int Kt = 0; Kt < 2; ++Kt) {
        const _Float16* p = img + (32 * Kt + 8 * q) * SB + 16 * J + n;
        half8 b;
#pragma unroll
        for (int j = 0; j < 8; ++j) b[j] = p[j * SB];
        B[Kt] = b;
    }
#pragma unroll
    for (int I = 0; I < 4; ++I) {
        float4e c = {0.0f, 0.0f, 0.0f, 0.0f};
        c = __builtin_amdgcn_mfma_f32_16x16x32_f16(Hf[I][0], B[0], c, 0, 0, 0);
        c = __builtin_amdgcn_mfma_f32_16x16x32_f16(Hf[I][1], B[1], c, 0, 0, 0);
        acc[I] = c;
    }
}

// Write acc (C-layout: row=16I+4q+r, col=16J+n [m89]) TRANSPOSED:
// img[(16J+n)*SB + 16I+4q .. +3] — one 8B half4 write per I, conflict-free.
__device__ __forceinline__ void img_write_T(_Float16* __restrict__ img,
                                            int n, int q, int J,
                                            const float4e acc[4]) {
#pragma unroll
    for (int I = 0; I < 4; ++I) {
        half4 h;
        h[0] = (_Float16)acc[I][0];
        h[1] = (_Float16)acc[I][1];
        h[2] = (_Float16)acc[I][2];
        h[3] = (_Float16)acc[I][3];
        *(half4*)(img + (16 * J + n) * SB + 16 * I + 4 * q) = h;
    }
}

// One BLOCK per row, 4 waves; wave J owns columns 16J..16J+15 of each stage.
// FWHT_4096 = H64 (x) H64: with M[a][b] = v[64a+b], FWHT(v) = H.M.H.
//   img0 = M -> P = H.M -> img1 = P^T -> Z^T = H.P^T  (FWHT1)
//   acc *= g   (g computed IN-REGISTER: e = 1024J + 64n + 16I + 4q + r)
//   img0 = Z' -> R = H.Z' -> img1 = R^T -> Y^T = H.R^T (FWHT2)
//   out[e] = s1[e] * Y^T element.  Single kernel node: no d_ws, no precompute.
__global__ void __launch_bounds__(256, 4)
whvi_mfma(const float* __restrict__ x, const float* __restrict__ s1,
          const float* __restrict__ s2, const float* __restrict__ eps,
          const float* __restrict__ g_mu, const float* __restrict__ g_rho,
          float* __restrict__ out) {
    const int tid  = threadIdx.x;
    const int lane = tid & 63;
    const int J    = tid >> 6;            // wave id = column tile
    const int row  = blockIdx.x;          // 2048 blocks, 1 row each
    const int n = lane & 15, q = lane >> 4;

    __shared__ __align__(16) _Float16 img[2][64 * SB];   // 2 x 8.7 KB

    const float4e* __restrict__ xr  = (const float4e*)(x + (size_t)row * DIM);
    const float4e* __restrict__ s2v = (const float4e*)s2;

    // ---- issue row loads first (4 b128/thread in flight across the block)
    float4e xv[4], sv[4];
#pragma unroll
    for (int k = 0; k < 4; ++k) xv[k] = xr[tid + 256 * k];
#pragma unroll
    for (int k = 0; k < 4; ++k) sv[k] = s2v[tid + 256 * k];

    // ---- issue this wave's g-component loads early (12 b128, L2-hot 48 KB)
    float4e ev[4], mv[4], rv[4];
#pragma unroll
    for (int I = 0; I < 4; ++I) {
        const int e = 1024 * J + 64 * n + 16 * I + 4 * q;
        ev[I] = *(const float4e*)(eps   + e);
        mv[I] = *(const float4e*)(g_mu  + e);
        rv[I] = *(const float4e*)(g_rho + e);
    }

    // ---- H fragments (A-layout: m=lane&15, k=8q+j [m120]); hides load latency
    half8 Hf[4][2];
#pragma unroll
    for (int I = 0; I < 4; ++I)
#pragma unroll
        for (int Kt = 0; Kt < 2; ++Kt) {
            half8 h;
#pragma unroll
            for (int j = 0; j < 8; ++j) {
                int rr = 16 * I + n, cc = 32 * Kt + 8 * q + j;
                h[j] = (__popc(rr & cc) & 1) ? (_Float16)(-1.0f) : (_Float16)(1.0f);
            }
            Hf[I][Kt] = h;
        }

    // ---- img0 = M = s2*x: thread's float4 covers e=4ft..+3 -> img[a*SB+b],
    // a = e>>6 = 4J+16k+q, b = e&63 = 4n  (conflict-free half4 writes)
#pragma unroll
    for (int k = 0; k < 4; ++k) {
        float4e p = xv[k] * sv[k];
        half4 h;
        h[0] = (_Float16)p[0]; h[1] = (_Float16)p[1];
        h[2] = (_Float16)p[2]; h[3] = (_Float16)p[3];
        *(half4*)(&img[0][(4 * J + 16 * k + q) * SB + 4 * n]) = h;
    }
    __syncthreads();

    float4e acc[4];

    hx_stage(img[0], n, q, J, Hf, acc);   // P = H.M   (cols 16J..)
    img_write_T(img[1], n, q, J, acc);    // img1 = P^T

    // ---- compute g in-register while waiting at the barrier:
    // g = g_mu + softplus(g_rho)*eps, softplus = log1p(exp(.)), rho in [-5,-4]
    float4e gg[4];
#pragma unroll
    for (int I = 0; I < 4; ++I) {
#pragma unroll
        for (int c = 0; c < 4; ++c)
            gg[I][c] = fmaf(log1pf(expf(rv[I][c])), ev[I][c], mv[I][c]);
    }
    __syncthreads();

    hx_stage(img[1], n, q, J, Hf, acc);   // Z^T = H.P^T
#pragma unroll
    for (int I = 0; I < 4; ++I)
        acc[I] *= gg[I];                  // Z' = g (.) Z  (element e matches)
    img_write_T(img[0], n, q, J, acc);    // img0 = Z'
    __syncthreads();

    hx_stage(img[0], n, q, J, Hf, acc);   // R = H.Z'
    img_write_T(img[1], n, q, J, acc);    // img1 = R^T
    __syncthreads();

    hx_stage(img[1], n, q, J, Hf, acc);   // Y^T = H.R^T

    // ---- s1 scale + store: e = 1024J + 64n + 16I + 4q (+r), b128 stores
    float* __restrict__ orow = out + (size_t)row * DIM;
#pragma unroll
    for (int I = 0; I < 4; ++I) {
        const int e = 1024 * J + 64 * n + 16 * I + 4 * q;
        const float4e sg = *(const float4e*)(s1 + e);
        *(float4e*)(orow + e) = acc[I] * sg;
    }
}

extern "C" void kernel_launch(void* const* d_in, const int* in_sizes, int n_in,
                              void* d_out, int out_size, void* d_ws, size_t ws_size,
                              hipStream_t stream) {
    // setup_inputs order: x, epsilon, s1, s2, g_mu, g_rho
    const float* x     = (const float*)d_in[0];
    const float* eps   = (const float*)d_in[1];
    const float* s1    = (const float*)d_in[2];
    const float* s2    = (const float*)d_in[3];
    const float* g_mu  = (const float*)d_in[4];
    const float* g_rho = (const float*)d_in[5];
    float* out = (float*)d_out;

    // Single fused kernel node: 2048 rows, 1 block/row, 4 waves/block.
    whvi_mfma<<<ROWS, 256, 0, stream>>>(x, s1, s2, eps, g_mu, g_rho, out);
}

// Round 9
// 100.049 us; speedup vs baseline: 1.1424x; 1.1424x over previous
//
#include <hip/hip_runtime.h>
#include <math.h>

#define DIM 4096
#define ROWS 2048
#define SB 68   // LDS image stride in halves: %4==0 -> 8B-aligned half4 writes;
                // b16 frag reads conflict-free (bank = 16(q&1)+2j+8J+(n>>1))

typedef _Float16 half8  __attribute__((ext_vector_type(8)));
typedef _Float16 half4  __attribute__((ext_vector_type(4)));
typedef float    float4e __attribute__((ext_vector_type(4)));

// ---- pre-kernel: g[e] = g_mu + softplus(g_rho) * eps  (plain order, 16 KB)
__global__ void g_precompute(const float* __restrict__ eps,
                             const float* __restrict__ g_mu,
                             const float* __restrict__ g_rho,
                             float* __restrict__ g) {
    int i = blockIdx.x * blockDim.x + threadIdx.x;
    g[i] = fmaf(log1pf(expf(g_rho[i])), eps[i], g_mu[i]);
}

// One "H on the left" GEMM stage: acc(I,J) = sum_Kt H(I,Kt) x B(J,Kt),
// B read from the 64x64 fp16 image (img[a][b], b contiguous, stride SB):
// B[k][n'] = img[k][16J+n], k = 32Kt + 8q + j  (A/B layouts per m89/m120).
__device__ __forceinline__ void hx_stage(const _Float16* __restrict__ img,
                                         int n, int q, const half8 Hf[4][2],
                                         float4e acc[4][4]) {
    half8 B[4][2];
#pragma unroll
    for (int J = 0; J < 4; ++J)
#pragma unroll
        for (int Kt = 0; Kt < 2; ++Kt) {
            const _Float16* p = img + (32 * Kt + 8 * q) * SB + 16 * J + n;
            half8 b;
#pragma unroll
            for (int j = 0; j < 8; ++j) b[j] = p[j * SB];
            B[J][Kt] = b;
        }
#pragma unroll
    for (int I = 0; I < 4; ++I)
#pragma unroll
        for (int J = 0; J < 4; ++J) {
            float4e c = {0.0f, 0.0f, 0.0f, 0.0f};
            c = __builtin_amdgcn_mfma_f32_16x16x32_f16(Hf[I][0], B[J][0], c, 0, 0, 0);
            c = __builtin_amdgcn_mfma_f32_16x16x32_f16(Hf[I][1], B[J][1], c, 0, 0, 0);
            acc[I][J] = c;
        }
}

// Write acc (C-layout: row=16I+4q+r, col=16J+n [m89]) TRANSPOSED to the image:
// img[col][row] -> image = ACC^T. 4 contiguous rows -> one 8B half4 write.
__device__ __forceinline__ void img_write_T(_Float16* __restrict__ img,
                                            int n, int q, const float4e acc[4][4]) {
#pragma unroll
    for (int I = 0; I < 4; ++I)
#pragma unroll
        for (int J = 0; J < 4; ++J) {
            half4 h;
            h[0] = (_Float16)acc[I][J][0];
            h[1] = (_Float16)acc[I][J][1];
            h[2] = (_Float16)acc[I][J][2];
            h[3] = (_Float16)acc[I][J][3];
            *(half4*)(img + (16 * J + n) * SB + 16 * I + 4 * q) = h;
        }
}

// One wave per row. FWHT_4096 = H64 (x) H64: with M[a][b] = v[64a+b],
// FWHT(v) as matrix = H.M.H. Full op out = s1*FWHT(g*FWHT(s2*x)):
//   P = H.M          (img0 = M)
//   Z^T = H.P^T      (img1 = P^T)     Z = H M H  (FWHT1)
//   acc *= g         (g[e], e = 1024J + 64n + 16I + 4q + r  == Z^T element)
//   R = H.Z'         (img2 = Z')
//   Y^T = H.R^T      (img3 = R^T)     Y = H Z' H (FWHT2)
//   out[e] = s1[e] * Y^T element.
// All H-on-the-left: A operand is H fragments, exact +/-1 via popc parity.
// Wave-private image: NO barriers (per-wave DS pipe is in-order).
__global__ void __launch_bounds__(256, 2)
whvi_mfma(const float* __restrict__ x, const float* __restrict__ s1,
          const float* __restrict__ s2, const float* __restrict__ g,
          float* __restrict__ out) {
    const int lane = threadIdx.x & 63;
    const int wid  = threadIdx.x >> 6;
    const int row  = blockIdx.x * 4 + wid;     // 512 blocks x 4 waves = 2048 rows
    const int n = lane & 15, q = lane >> 4;

    __shared__ __align__(16) _Float16 lds[4 * 64 * SB];   // 34 KB/block
    _Float16* __restrict__ img = lds + wid * 64 * SB;     // wave-private

    const float4e* __restrict__ xr  = (const float4e*)(x + (size_t)row * DIM);
    const float4e* __restrict__ s2v = (const float4e*)s2;

    // ---- issue row loads first (32 b128 in flight)
    float4e xv[16], sv[16];
#pragma unroll
    for (int r = 0; r < 16; ++r) xv[r] = xr[64 * r + lane];
#pragma unroll
    for (int r = 0; r < 16; ++r) sv[r] = s2v[64 * r + lane];

    // ---- H fragments (A-layout: m=lane&15, k=8q+j [m120]); overlaps load latency
    half8 Hf[4][2];
#pragma unroll
    for (int I = 0; I < 4; ++I)
#pragma unroll
        for (int Kt = 0; Kt < 2; ++Kt) {
            half8 h;
#pragma unroll
            for (int j = 0; j < 8; ++j) {
                int rr = 16 * I + n, cc = 32 * Kt + 8 * q + j;
                h[j] = (__popc(rr & cc) & 1) ? (_Float16)(-1.0f) : (_Float16)(1.0f);
            }
            Hf[I][Kt] = h;
        }

    // ---- IMG0 = M = s2*x: element e=256r+4*lane+i -> img[(4r+q)*SB + 4n + i]
#pragma unroll
    for (int r = 0; r < 16; ++r) {
        float4e p = xv[r] * sv[r];
        half4 h;
        h[0] = (_Float16)p[0]; h[1] = (_Float16)p[1];
        h[2] = (_Float16)p[2]; h[3] = (_Float16)p[3];
        *(half4*)(img + (4 * r + q) * SB + 4 * n) = h;
    }

    float4e acc[4][4];

    hx_stage(img, n, q, Hf, acc);        // P = H.M
    img_write_T(img, n, q, acc);         // img = P^T   (in-order DS: safe reuse)
    hx_stage(img, n, q, Hf, acc);        // Z^T

    // ---- g multiply (Z^T element == g[e]); 16 KB array, L1/L2-hot b128 loads
#pragma unroll
    for (int I = 0; I < 4; ++I)
#pragma unroll
        for (int J = 0; J < 4; ++J) {
            const float4e gg = *(const float4e*)(g + 1024 * J + 64 * n + 16 * I + 4 * q);
            acc[I][J] *= gg;
        }

    img_write_T(img, n, q, acc);         // img = Z'
    hx_stage(img, n, q, Hf, acc);        // R = H.Z'
    img_write_T(img, n, q, acc);         // img = R^T
    hx_stage(img, n, q, Hf, acc);        // Y^T

    // ---- s1 scale + store: e = 1024J + 64n + 16I + 4q (+r): b128, line-covered
    float* __restrict__ orow = out + (size_t)row * DIM;
#pragma unroll
    for (int I = 0; I < 4; ++I)
#pragma unroll
        for (int J = 0; J < 4; ++J) {
            const int e = 1024 * J + 64 * n + 16 * I + 4 * q;
            const float4e sg = *(const float4e*)(s1 + e);
            *(float4e*)(orow + e) = acc[I][J] * sg;
        }
}

extern "C" void kernel_launch(void* const* d_in, const int* in_sizes, int n_in,
                              void* d_out, int out_size, void* d_ws, size_t ws_size,
                              hipStream_t stream) {
    // setup_inputs order: x, epsilon, s1, s2, g_mu, g_rho
    const float* x     = (const float*)d_in[0];
    const float* eps   = (const float*)d_in[1];
    const float* s1    = (const float*)d_in[2];
    const float* s2    = (const float*)d_in[3];
    const float* g_mu  = (const float*)d_in[4];
    const float* g_rho = (const float*)d_in[5];
    float* out = (float*)d_out;
    float* g   = (float*)d_ws;   // 4096 floats

    g_precompute<<<DIM / 256, 256, 0, stream>>>(eps, g_mu, g_rho, g);
    whvi_mfma<<<ROWS / 4, 256, 0, stream>>>(x, s1, s2, g, out);
}